// Round 1
// baseline (1080.670 us; speedup 1.0000x reference)
//
#include <hip/hip_runtime.h>

namespace {

constexpr int Bb   = 4;
constexpr int Nn   = 8192;
constexpr int Mm   = 8192;
constexpr int KNB  = 6;
constexpr int TILE = 256;
constexpr int MCHUNKS = 4;

// ---------------- init: mins -> +inf, accumulators -> 0 ----------------
__global__ void init_ws_kernel(unsigned* __restrict__ minArr, float* __restrict__ acc) {
    int i = blockIdx.x * blockDim.x + threadIdx.x;
    if (i < 2 * Bb * Nn) minArr[i] = 0x7f800000u;  // +inf bits
    if (i < 8) acc[i] = 0.0f;
}

// ---------------- chamfer directional min ----------------
// MODE 0: query = template+disp (pred_pos), db = target_pos
// MODE 1: query = target_pos,               db = template+disp
template <int MODE>
__global__ __launch_bounds__(256) void chamfer_min_kernel(
    const float* __restrict__ disp, const float* __restrict__ tmpl,
    const float* __restrict__ targ, unsigned* __restrict__ outMin) {
    __shared__ float4 sp[TILE];
    const int tid = threadIdx.x;
    const int b = blockIdx.z;
    const int n = blockIdx.x * 256 + tid;
    const int mBase = blockIdx.y * (Mm / MCHUNKS);

    float qx, qy, qz;
    {
        const long qb = (long)b * Nn * 3 + (long)n * 3;
        if (MODE == 0) {
            qx = tmpl[qb + 0] + disp[qb + 0];
            qy = tmpl[qb + 1] + disp[qb + 1];
            qz = tmpl[qb + 2] + disp[qb + 2];
        } else {
            qx = targ[qb + 0];
            qy = targ[qb + 1];
            qz = targ[qb + 2];
        }
    }

    float m0 = 1e38f, m1 = 1e38f, m2 = 1e38f, m3 = 1e38f;

    for (int t0 = 0; t0 < Mm / MCHUNKS; t0 += TILE) {
        __syncthreads();
        {
            const long db = (long)b * Mm * 3 + (long)(mBase + t0 + tid) * 3;
            float x, y, z;
            if (MODE == 0) {
                x = targ[db + 0]; y = targ[db + 1]; z = targ[db + 2];
            } else {
                x = tmpl[db + 0] + disp[db + 0];
                y = tmpl[db + 1] + disp[db + 1];
                z = tmpl[db + 2] + disp[db + 2];
            }
            sp[tid] = make_float4(x, y, z, 0.0f);
        }
        __syncthreads();

        #pragma unroll 4
        for (int j = 0; j < TILE; j += 4) {
            float4 p0 = sp[j + 0];
            float4 p1 = sp[j + 1];
            float4 p2 = sp[j + 2];
            float4 p3 = sp[j + 3];
            float dx, dy, dz, d2;
            dx = qx - p0.x; dy = qy - p0.y; dz = qz - p0.z;
            d2 = dx * dx + dy * dy + dz * dz; m0 = fminf(m0, d2);
            dx = qx - p1.x; dy = qy - p1.y; dz = qz - p1.z;
            d2 = dx * dx + dy * dy + dz * dz; m1 = fminf(m1, d2);
            dx = qx - p2.x; dy = qy - p2.y; dz = qz - p2.z;
            d2 = dx * dx + dy * dy + dz * dz; m2 = fminf(m2, d2);
            dx = qx - p3.x; dy = qy - p3.y; dz = qz - p3.z;
            d2 = dx * dx + dy * dy + dz * dz; m3 = fminf(m3, d2);
        }
    }

    float best = fminf(fminf(m0, m1), fminf(m2, m3));
    atomicMin(&outMin[(long)b * Nn + n], __float_as_uint(best));
}

// ---------------- KNN on template[0] + smoothness reg ----------------
__global__ __launch_bounds__(256) void knn_smooth_kernel(
    const float* __restrict__ tmpl, const float* __restrict__ disp,
    float* __restrict__ acc) {
    __shared__ float4 sp[TILE];
    __shared__ float red[256];
    const int tid = threadIdx.x;
    const int n = blockIdx.x * 256 + tid;

    const float qx = tmpl[n * 3 + 0];
    const float qy = tmpl[n * 3 + 1];
    const float qz = tmpl[n * 3 + 2];

    float nd[KNB + 1];
    int   ni[KNB + 1];
    #pragma unroll
    for (int k = 0; k <= KNB; ++k) { nd[k] = 1e38f; ni[k] = 0; }

    for (int t0 = 0; t0 < Nn; t0 += TILE) {
        __syncthreads();
        {
            const long db = (long)(t0 + tid) * 3;
            sp[tid] = make_float4(tmpl[db + 0], tmpl[db + 1], tmpl[db + 2], 0.0f);
        }
        __syncthreads();

        for (int j = 0; j < TILE; ++j) {
            float4 p = sp[j];
            float dx = qx - p.x, dy = qy - p.y, dz = qz - p.z;
            float d2 = dx * dx + dy * dy + dz * dz;
            if (d2 < nd[KNB]) {
                nd[KNB] = d2; ni[KNB] = t0 + j;
                // bubble down; strict < keeps lower index first on ties (top_k semantics)
                #pragma unroll
                for (int p2 = KNB; p2 > 0; --p2) {
                    if (nd[p2] < nd[p2 - 1]) {
                        float tf = nd[p2]; nd[p2] = nd[p2 - 1]; nd[p2 - 1] = tf;
                        int   ti = ni[p2]; ni[p2] = ni[p2 - 1]; ni[p2 - 1] = ti;
                    }
                }
            }
        }
    }

    // slot 0 is self (d2 == 0 exactly); neighbors are slots 1..KNB
    float s = 0.0f;
    #pragma unroll
    for (int k = 1; k <= KNB; ++k) {
        const int j = ni[k];
        #pragma unroll
        for (int b = 0; b < Bb; ++b) {
            const float* dn = disp + ((long)b * Nn + n) * 3;
            const float* dj = disp + ((long)b * Nn + j) * 3;
            float dx = dj[0] - dn[0];
            float dy = dj[1] - dn[1];
            float dz = dj[2] - dn[2];
            s += dx * dx + dy * dy + dz * dz;
        }
    }

    red[tid] = s;
    __syncthreads();
    for (int w = 128; w > 0; w >>= 1) {
        if (tid < w) red[tid] += red[tid + w];
        __syncthreads();
    }
    if (tid == 0) atomicAdd(&acc[3], red[0]);
}

// ---------------- mat loss + disp reg ----------------
__global__ __launch_bounds__(256) void matdisp_kernel(
    const float* __restrict__ pm, const float* __restrict__ tm,
    const float* __restrict__ dp, float* __restrict__ acc) {
    const int tid = threadIdx.x;
    const int stride = gridDim.x * blockDim.x;
    float sm = 0.0f, sd = 0.0f;
    for (int i = blockIdx.x * blockDim.x + tid; i < Bb * Nn * 4; i += stride) {
        float d = pm[i] - tm[i];
        sm += d * d;
    }
    for (int i = blockIdx.x * blockDim.x + tid; i < Bb * Nn * 3; i += stride) {
        float v = dp[i];
        sd += v * v;
    }
    __shared__ float r1[256], r2[256];
    r1[tid] = sm; r2[tid] = sd;
    __syncthreads();
    for (int w = 128; w > 0; w >>= 1) {
        if (tid < w) { r1[tid] += r1[tid + w]; r2[tid] += r2[tid + w]; }
        __syncthreads();
    }
    if (tid == 0) {
        atomicAdd(&acc[1], r1[0]);
        atomicAdd(&acc[2], r2[0]);
    }
}

// ---------------- sum sqrt of mins (both directions, contiguous) ----------------
__global__ __launch_bounds__(256) void reduce_mins_kernel(
    const float* __restrict__ minArr, float* __restrict__ acc) {
    const int tid = threadIdx.x;
    const int stride = gridDim.x * blockDim.x;
    float s = 0.0f;
    for (int i = blockIdx.x * blockDim.x + tid; i < 2 * Bb * Nn; i += stride) {
        s += sqrtf(fmaxf(minArr[i], 1e-12f));
    }
    __shared__ float red[256];
    red[tid] = s;
    __syncthreads();
    for (int w = 128; w > 0; w >>= 1) {
        if (tid < w) red[tid] += red[tid + w];
        __syncthreads();
    }
    if (tid == 0) atomicAdd(&acc[0], red[0]);
}

// ---------------- finalize ----------------
__global__ void finalize_kernel(const float* __restrict__ acc, float* __restrict__ out) {
    if (threadIdx.x == 0 && blockIdx.x == 0) {
        float cd  = acc[0] / (2.0f * Bb * Nn);            // (sum_p2t + sum_t2p)/(2*B*N), N==M
        float mat = acc[1] / (float)(Bb * Nn * 4);
        float dr  = acc[2] / (float)(Bb * Nn * 3);
        float sm  = acc[3] / (float)(Bb * Nn * KNB * 3);
        out[0] = 1.0f * cd + 0.1f * mat + 0.01f * dr + 0.005f * sm;
    }
}

}  // namespace

extern "C" void kernel_launch(void* const* d_in, const int* in_sizes, int n_in,
                              void* d_out, int out_size, void* d_ws, size_t ws_size,
                              hipStream_t stream) {
    const float* pred_disp  = (const float*)d_in[0];
    const float* pred_mat   = (const float*)d_in[1];
    const float* target_pos = (const float*)d_in[2];
    const float* target_mat = (const float*)d_in[3];
    const float* tmpl       = (const float*)d_in[4];

    float* ws = (float*)d_ws;
    unsigned* minP = (unsigned*)ws;           // B*N entries (pred->target d2 mins)
    unsigned* minT = minP + Bb * Nn;          // B*M entries (target->pred d2 mins)
    float* acc = ws + 2 * Bb * Nn;            // 8 accumulators

    init_ws_kernel<<<(2 * Bb * Nn) / 256, 256, 0, stream>>>(minP, acc);

    dim3 cgrid(Nn / 256, MCHUNKS, Bb);
    chamfer_min_kernel<0><<<cgrid, 256, 0, stream>>>(pred_disp, tmpl, target_pos, minP);
    chamfer_min_kernel<1><<<cgrid, 256, 0, stream>>>(pred_disp, tmpl, target_pos, minT);

    knn_smooth_kernel<<<Nn / 256, 256, 0, stream>>>(tmpl, pred_disp, acc);

    matdisp_kernel<<<256, 256, 0, stream>>>(pred_mat, target_mat, pred_disp, acc);

    reduce_mins_kernel<<<64, 256, 0, stream>>>((const float*)minP, acc);

    finalize_kernel<<<1, 64, 0, stream>>>(acc, (float*)d_out);
}

// Round 2
// 136.919 us; speedup vs baseline: 7.8928x; 7.8928x over previous
//
#include <hip/hip_runtime.h>

namespace {

constexpr int Bb   = 4;
constexpr int Nn   = 8192;
constexpr int Mm   = 8192;
constexpr int KNB  = 6;
constexpr int TILE = 256;
constexpr int MCHUNKS = 16;

__device__ inline unsigned long long shflx64(unsigned long long v, int m) {
    unsigned lo = (unsigned)v, hi = (unsigned)(v >> 32);
    lo = (unsigned)__shfl_xor((int)lo, m, 64);
    hi = (unsigned)__shfl_xor((int)hi, m, 64);
    return ((unsigned long long)hi << 32) | lo;
}

// ---------------- init: mins -> +inf, accumulators -> 0 ----------------
__global__ void init_ws_kernel(unsigned* __restrict__ minArr, float* __restrict__ acc) {
    int i = blockIdx.x * blockDim.x + threadIdx.x;
    if (i < 2 * Bb * Nn) minArr[i] = 0x7f800000u;  // +inf bits
    if (i < 8) acc[i] = 0.0f;
}

// ---------------- chamfer directional min ----------------
// MODE 0: query = template+disp (pred_pos), db = target_pos
// MODE 1: query = target_pos,               db = template+disp
// Inner form matches reference's xx + yy - 2xy:  d2 = q2 + 2*(h - q.p), h=|p|^2/2
template <int MODE>
__global__ __launch_bounds__(256) void chamfer_min_kernel(
    const float* __restrict__ disp, const float* __restrict__ tmpl,
    const float* __restrict__ targ, unsigned* __restrict__ outMin) {
    __shared__ float4 sp[TILE];
    const int tid = threadIdx.x;
    const int b = blockIdx.z;
    const int n = blockIdx.x * 256 + tid;
    const int mBase = blockIdx.y * (Mm / MCHUNKS);

    float qx, qy, qz;
    {
        const long qb = (long)b * Nn * 3 + (long)n * 3;
        if (MODE == 0) {
            qx = tmpl[qb + 0] + disp[qb + 0];
            qy = tmpl[qb + 1] + disp[qb + 1];
            qz = tmpl[qb + 2] + disp[qb + 2];
        } else {
            qx = targ[qb + 0];
            qy = targ[qb + 1];
            qz = targ[qb + 2];
        }
    }
    const float q2 = qx * qx + qy * qy + qz * qz;
    const float nqx = -qx, nqy = -qy, nqz = -qz;

    float m0 = 1e38f, m1 = 1e38f, m2 = 1e38f, m3 = 1e38f;

    for (int t0 = 0; t0 < Mm / MCHUNKS; t0 += TILE) {
        __syncthreads();
        {
            const long db = (long)b * Mm * 3 + (long)(mBase + t0 + tid) * 3;
            float x, y, z;
            if (MODE == 0) {
                x = targ[db + 0]; y = targ[db + 1]; z = targ[db + 2];
            } else {
                x = tmpl[db + 0] + disp[db + 0];
                y = tmpl[db + 1] + disp[db + 1];
                z = tmpl[db + 2] + disp[db + 2];
            }
            sp[tid] = make_float4(x, y, z, 0.5f * (x * x + y * y + z * z));
        }
        __syncthreads();

        #pragma unroll 8
        for (int j = 0; j < TILE; j += 4) {
            float4 p0 = sp[j + 0];
            float4 p1 = sp[j + 1];
            float4 p2 = sp[j + 2];
            float4 p3 = sp[j + 3];
            float s;
            s = fmaf(p0.x, nqx, fmaf(p0.y, nqy, fmaf(p0.z, nqz, p0.w))); m0 = fminf(m0, s);
            s = fmaf(p1.x, nqx, fmaf(p1.y, nqy, fmaf(p1.z, nqz, p1.w))); m1 = fminf(m1, s);
            s = fmaf(p2.x, nqx, fmaf(p2.y, nqy, fmaf(p2.z, nqz, p2.w))); m2 = fminf(m2, s);
            s = fmaf(p3.x, nqx, fmaf(p3.y, nqy, fmaf(p3.z, nqz, p3.w))); m3 = fminf(m3, s);
        }
    }

    float smin = fminf(fminf(m0, m1), fminf(m2, m3));
    float d2 = fmaf(2.0f, smin, q2);
    atomicMin(&outMin[(long)b * Nn + n], __float_as_uint(d2));
}

// ---------------- KNN on template[0] + smoothness reg (wave-per-query) ----------------
__global__ __launch_bounds__(256) void knn_smooth_kernel(
    const float* __restrict__ tmpl, const float* __restrict__ disp,
    float* __restrict__ acc) {
    const int lane = threadIdx.x & 63;
    const int wid  = threadIdx.x >> 6;
    const int q    = blockIdx.x * 4 + wid;

    const float qx = tmpl[q * 3 + 0];
    const float qy = tmpl[q * 3 + 1];
    const float qz = tmpl[q * 3 + 2];

    const unsigned long long MAXK = ~0ULL;
    unsigned long long l0 = MAXK, l1 = MAXK, l2 = MAXK, l3 = MAXK,
                       l4 = MAXK, l5 = MAXK, l6 = MAXK;

    // each lane scans 128 points, strided for coalescing; key=(d2bits<<32)|idx
    for (int i = 0; i < Nn / 64; ++i) {
        const int p = i * 64 + lane;
        const float px = tmpl[p * 3 + 0];
        const float py = tmpl[p * 3 + 1];
        const float pz = tmpl[p * 3 + 2];
        const float dx = qx - px, dy = qy - py, dz = qz - pz;
        const float d2 = dx * dx + dy * dy + dz * dz;
        unsigned long long key =
            ((unsigned long long)__float_as_uint(d2) << 32) | (unsigned)p;
        if (key < l6) {
            l6 = key;
            if (l6 < l5) { auto t = l5; l5 = l6; l6 = t; }
            if (l5 < l4) { auto t = l4; l4 = l5; l5 = t; }
            if (l4 < l3) { auto t = l3; l3 = l4; l4 = t; }
            if (l3 < l2) { auto t = l2; l2 = l3; l3 = t; }
            if (l2 < l1) { auto t = l1; l1 = l2; l2 = t; }
            if (l1 < l0) { auto t = l0; l0 = l1; l1 = t; }
        }
    }

    // 7-round tournament: global 7 smallest keys across the wave.
    // best[0] is self (d2==0, lowest idx on ties — matches top_k stability).
    unsigned long long best[7];
    #pragma unroll
    for (int t = 0; t < 7; ++t) {
        unsigned long long h = l0;
        #pragma unroll
        for (int off = 32; off; off >>= 1) {
            unsigned long long o = shflx64(h, off);
            h = (o < h) ? o : h;
        }
        best[t] = h;
        const bool pop = (l0 == h);
        l0 = pop ? l1 : l0; l1 = pop ? l2 : l1; l2 = pop ? l3 : l2;
        l3 = pop ? l4 : l3; l4 = pop ? l5 : l4; l5 = pop ? l6 : l5;
        l6 = pop ? MAXK : l6;
    }

    // smoothness: lanes 0..23 -> (neighbor k=1..6, batch b=0..3)
    float s = 0.0f;
    if (lane < 24) {
        const int kk = lane >> 2;   // 0..5
        const int b  = lane & 3;
        int j = (int)(unsigned)best[1];
        if (kk == 1) j = (int)(unsigned)best[2];
        if (kk == 2) j = (int)(unsigned)best[3];
        if (kk == 3) j = (int)(unsigned)best[4];
        if (kk == 4) j = (int)(unsigned)best[5];
        if (kk == 5) j = (int)(unsigned)best[6];
        const float* dn = disp + ((long)b * Nn + q) * 3;
        const float* dj = disp + ((long)b * Nn + j) * 3;
        const float ddx = dj[0] - dn[0];
        const float ddy = dj[1] - dn[1];
        const float ddz = dj[2] - dn[2];
        s = ddx * ddx + ddy * ddy + ddz * ddz;
    }
    #pragma unroll
    for (int off = 32; off; off >>= 1) s += __shfl_xor(s, off, 64);

    __shared__ float wsum[4];
    if (lane == 0) wsum[wid] = s;
    __syncthreads();
    if (threadIdx.x == 0)
        atomicAdd(&acc[3], wsum[0] + wsum[1] + wsum[2] + wsum[3]);
}

// ---------------- mat loss + disp reg ----------------
__global__ __launch_bounds__(256) void matdisp_kernel(
    const float* __restrict__ pm, const float* __restrict__ tm,
    const float* __restrict__ dp, float* __restrict__ acc) {
    const int tid = threadIdx.x;
    const int stride = gridDim.x * blockDim.x;
    float sm = 0.0f, sd = 0.0f;
    for (int i = blockIdx.x * blockDim.x + tid; i < Bb * Nn * 4; i += stride) {
        float d = pm[i] - tm[i];
        sm += d * d;
    }
    for (int i = blockIdx.x * blockDim.x + tid; i < Bb * Nn * 3; i += stride) {
        float v = dp[i];
        sd += v * v;
    }
    __shared__ float r1[256], r2[256];
    r1[tid] = sm; r2[tid] = sd;
    __syncthreads();
    for (int w = 128; w > 0; w >>= 1) {
        if (tid < w) { r1[tid] += r1[tid + w]; r2[tid] += r2[tid + w]; }
        __syncthreads();
    }
    if (tid == 0) {
        atomicAdd(&acc[1], r1[0]);
        atomicAdd(&acc[2], r2[0]);
    }
}

// ---------------- sum sqrt of mins (both directions, contiguous) ----------------
__global__ __launch_bounds__(256) void reduce_mins_kernel(
    const float* __restrict__ minArr, float* __restrict__ acc) {
    const int tid = threadIdx.x;
    const int stride = gridDim.x * blockDim.x;
    float s = 0.0f;
    for (int i = blockIdx.x * blockDim.x + tid; i < 2 * Bb * Nn; i += stride) {
        s += sqrtf(fmaxf(minArr[i], 1e-12f));
    }
    __shared__ float red[256];
    red[tid] = s;
    __syncthreads();
    for (int w = 128; w > 0; w >>= 1) {
        if (tid < w) red[tid] += red[tid + w];
        __syncthreads();
    }
    if (tid == 0) atomicAdd(&acc[0], red[0]);
}

// ---------------- finalize ----------------
__global__ void finalize_kernel(const float* __restrict__ acc, float* __restrict__ out) {
    if (threadIdx.x == 0 && blockIdx.x == 0) {
        float cd  = acc[0] / (2.0f * Bb * Nn);            // (sum_p2t + sum_t2p)/(2*B*N), N==M
        float mat = acc[1] / (float)(Bb * Nn * 4);
        float dr  = acc[2] / (float)(Bb * Nn * 3);
        float sm  = acc[3] / (float)(Bb * Nn * KNB * 3);
        out[0] = 1.0f * cd + 0.1f * mat + 0.01f * dr + 0.005f * sm;
    }
}

}  // namespace

extern "C" void kernel_launch(void* const* d_in, const int* in_sizes, int n_in,
                              void* d_out, int out_size, void* d_ws, size_t ws_size,
                              hipStream_t stream) {
    const float* pred_disp  = (const float*)d_in[0];
    const float* pred_mat   = (const float*)d_in[1];
    const float* target_pos = (const float*)d_in[2];
    const float* target_mat = (const float*)d_in[3];
    const float* tmpl       = (const float*)d_in[4];

    float* ws = (float*)d_ws;
    unsigned* minP = (unsigned*)ws;           // B*N entries (pred->target d2 mins)
    unsigned* minT = minP + Bb * Nn;          // B*M entries (target->pred d2 mins)
    float* acc = ws + 2 * Bb * Nn;            // 8 accumulators

    init_ws_kernel<<<(2 * Bb * Nn) / 256, 256, 0, stream>>>(minP, acc);

    dim3 cgrid(Nn / 256, MCHUNKS, Bb);
    chamfer_min_kernel<0><<<cgrid, 256, 0, stream>>>(pred_disp, tmpl, target_pos, minP);
    chamfer_min_kernel<1><<<cgrid, 256, 0, stream>>>(pred_disp, tmpl, target_pos, minT);

    knn_smooth_kernel<<<Nn / 4 / 64, 256, 0, stream>>>(tmpl, pred_disp, acc);

    matdisp_kernel<<<256, 256, 0, stream>>>(pred_mat, target_mat, pred_disp, acc);

    reduce_mins_kernel<<<64, 256, 0, stream>>>((const float*)minP, acc);

    finalize_kernel<<<1, 64, 0, stream>>>(acc, (float*)d_out);
}